// Round 9
// baseline (1151.672 us; speedup 1.0000x reference)
//
#include <hip/hip_runtime.h>
#include <hip/hip_fp16.h>
#include <stdint.h>

#define VV 32000
#define HH 256
#define BB 32
#define TT 128
#define VH 32256   // V + H
#define NTILE 4000 // (4096/128) * (32000/256)

typedef _Float16 f16;
typedef _Float16 f16x2 __attribute__((ext_vector_type(2)));
typedef _Float16 f16x8 __attribute__((ext_vector_type(8)));
typedef float f32x4 __attribute__((ext_vector_type(4)));

static __device__ __forceinline__ float dot2f(uint32_t w, uint32_t h, float acc){
  f16x2 a = __builtin_bit_cast(f16x2, w);
  f16x2 b = __builtin_bit_cast(f16x2, h);
#if __has_builtin(__builtin_amdgcn_fdot2)
  return __builtin_amdgcn_fdot2(a, b, acc, false);
#else
  acc = fmaf((float)a[0], (float)b[0], acc);
  acc = fmaf((float)a[1], (float)b[1], acc);
  return acc;
#endif
}

// ---------------- control-block init (done[t] at ctl[t*16], arrival=ctl[2048], tiles=ctl[2049])
__global__ void k_init(int* __restrict__ ctl){
  int i = blockIdx.x*1024 + threadIdx.x;
  if (i < 2050) ctl[i] = 0;
}

// ---------------- gather: g[t*32+b][o] = W_gate[row][tok] + bias
__global__ void k_gather(const int* __restrict__ X,
                         const float* __restrict__ Wz, const float* __restrict__ bz,
                         const float* __restrict__ Wr, const float* __restrict__ br,
                         const float* __restrict__ Wh, const float* __restrict__ bh,
                         float* __restrict__ g_buf){
  int tb = blockIdx.x;              // t*32 + b
  int t = tb >> 5, b = tb & 31;
  int tok = X[b*TT + t];
  int o = threadIdx.x;              // 0..255
  g_buf[(size_t)tb*768 + o]       = Wz[(size_t)o*VH + tok] + bz[o];
  g_buf[(size_t)tb*768 + 256 + o] = Wr[(size_t)o*VH + tok] + br[o];
  g_buf[(size_t)tb*768 + 512 + o] = Wh[(size_t)o*VH + tok] + bh[o];
}

// ---------------- pack recurrent weights for 512-thread recurrence layout
// thread t: ko=t&7, no=t>>3 in [0,64)
// ol<8 -> o=no*8+ol (o<256: Wz row o; else Wr row o-256); ol in [8,12): Wh row no*4+(ol-8)
__global__ void k_pack(const float* __restrict__ Wz, const float* __restrict__ Wr,
                       const float* __restrict__ Wh, uint32_t* __restrict__ Wpack){
  int idx = blockIdx.x*256 + threadIdx.x;
  if (idx >= 512*192) return;
  int t = idx / 192, rem = idx - t*192;
  int ol = rem >> 4, p = rem & 15;
  int ko = t & 7, no = t >> 3;
  int k = ko*32 + p*2;
  const float* W; int row;
  if (ol < 8){ int o = no*8 + ol; if (o < 256){ W = Wz; row = o; } else { W = Wr; row = o - 256; } }
  else { W = Wh; row = no*4 + (ol - 8); }
  float a = W[(size_t)row*VH + VV + k];
  float c = W[(size_t)row*VH + VV + k + 1];
  f16x2 v; v[0] = (f16)a; v[1] = (f16)c;
  Wpack[idx] = __builtin_bit_cast(uint32_t, v);
}

// ---------------- fused producer/consumer: 256 blocks x 512 thr, 1 block/CU
// waves_per_eu(2,2): 2 waves/EU -> 256-VGPR budget (round-8-validated for the producer path)
__global__ __launch_bounds__(512)
__attribute__((amdgpu_waves_per_eu(2, 2)))
void k_fused(const float* __restrict__ H0,
    const uint32_t* __restrict__ Wpack, const float* __restrict__ g_buf,
    const float* __restrict__ Wo, const float* __restrict__ bo,
    f16* __restrict__ Hn16, float* __restrict__ Y, float* __restrict__ hf_out,
    int* __restrict__ ctl){
  __shared__ __align__(16) char smem[49152];
  __shared__ int sh_role;
  __shared__ int sh_tile;
  const int tid = threadIdx.x;
  if (tid == 0) sh_role = atomicAdd(&ctl[2048], 1);
  __syncthreads();
  const int role = sh_role;

  if (role < BB){
    // ================= producer: recurrence for batch b = role (round-8 structure) =====
    const int b = role;
    uint32_t* hs16  = (uint32_t*)smem;           // 512 B: Hs as f16 pairs
    f16*      rHs16 = (f16*)(smem + 512);        // 512 B: r*Hs as f16
    float*    hs32  = (float*)(smem + 1024);     // 1 KiB: Hs f32 (state of record)
    float*    z_s   = (float*)(smem + 2048);     // 1 KiB: z gate
    const int ko = tid & 7, no = tid >> 3;       // no in [0,64)

    uint32_t w[12][16];
    {
      const uint4* src = (const uint4*)(Wpack + (size_t)tid*192);
      #pragma unroll
      for (int j=0;j<48;j++){
        uint4 v = src[j];
        int f = j*4;
        w[(f+0)>>4][(f+0)&15] = v.x;
        w[(f+1)>>4][(f+1)&15] = v.y;
        w[(f+2)>>4][(f+2)&15] = v.z;
        w[(f+3)>>4][(f+3)&15] = v.w;
      }
    }

    if (tid < 256) hs32[tid] = H0[b*HH + tid];
    __syncthreads();
    if (tid < 128){
      f16x2 v; v[0] = (f16)hs32[2*tid]; v[1] = (f16)hs32[2*tid+1];
      hs16[tid] = __builtin_bit_cast(uint32_t, v);
    }
    __syncthreads();

    const int gi1 = no*8 + ko;
    const int gi2 = 512 + no*4 + (ko & 3);
    float g1 = g_buf[(size_t)b*768 + gi1];
    float g2 = g_buf[(size_t)b*768 + gi2];
    float g1n = 0.f, g2n = 0.f;

    for (int t = 0; t < TT; t++){
      if (t < TT-1){
        const float* gn = g_buf + (size_t)((t+1)*BB + b)*768;
        g1n = gn[gi1];
        g2n = gn[gi2];
      }

      // ---- phase 1: z (no<32) and r (no>=32), 8 outputs per group
      uint32_t hp[16];
      {
        const uint2* hsp = (const uint2*)hs16;
        #pragma unroll
        for (int j=0;j<8;j++){ uint2 v = hsp[ko*8 + j]; hp[2*j] = v.x; hp[2*j+1] = v.y; }
      }
      float acc[8];
      #pragma unroll
      for (int ol=0;ol<8;ol++) acc[ol] = 0.f;
      #pragma unroll
      for (int p=0;p<16;p++)
        #pragma unroll
        for (int ol=0;ol<8;ol++)
          acc[ol] = dot2f(w[ol][p], hp[p], acc[ol]);
      #pragma unroll
      for (int ol=0;ol<8;ol++){
        float v2 = acc[ol];
        v2 += __shfl_xor(v2, 1);
        v2 += __shfl_xor(v2, 2);
        v2 += __shfl_xor(v2, 4);
        acc[ol] = v2;
      }
      {
        float sel = acc[0];
        #pragma unroll
        for (int ol=1;ol<8;ol++) sel = (ko == ol) ? acc[ol] : sel;
        float pre = sel + g1;
        float s = 1.f / (1.f + __expf(-pre));
        int o = no*8 + ko;
        if (no < 32){
          z_s[o] = s;
        } else {
          int op = o - 256;
          rHs16[op] = (f16)(s * hs32[op]);
        }
      }
      __syncthreads();

      // ---- phase 2
      uint32_t rp[16];
      {
        const uint2* rpp = (const uint2*)rHs16;
        #pragma unroll
        for (int j=0;j<8;j++){ uint2 v = rpp[ko*8 + j]; rp[2*j] = v.x; rp[2*j+1] = v.y; }
      }
      float a2[4];
      #pragma unroll
      for (int oi=0;oi<4;oi++) a2[oi] = 0.f;
      #pragma unroll
      for (int p=0;p<16;p++)
        #pragma unroll
        for (int oi=0;oi<4;oi++)
          a2[oi] = dot2f(w[8+oi][p], rp[p], a2[oi]);
      #pragma unroll
      for (int oi=0;oi<4;oi++){
        float v2 = a2[oi];
        v2 += __shfl_xor(v2, 1);
        v2 += __shfl_xor(v2, 2);
        v2 += __shfl_xor(v2, 4);
        a2[oi] = v2;
      }
      if (ko < 4){
        float sel = a2[0];
        #pragma unroll
        for (int oi=1;oi<4;oi++) sel = (ko == oi) ? a2[oi] : sel;
        int o = no*4 + ko;
        float pre = sel + g2;
        float ax = fabsf(pre);
        float e = __expf(2.f*ax);
        float th = 1.f - 2.f/(e + 1.f);
        th = copysignf(th, pre);
        float z = z_s[o];
        float hn = z*th + (1.f - z)*hs32[o];
        hs32[o] = hn;
        ((f16*)hs16)[o] = (f16)hn;
        Hn16[(size_t)(t*BB + b)*HH + o] = (f16)hn;
        if (t == TT-1) hf_out[b*HH + o] = hn;
      }
      g1 = g1n; g2 = g2n;
      __syncthreads();
      if (tid == 0){ __threadfence(); atomicAdd(&ctl[t*16], 1); }
    }
  } else {
    // ================= consumer: Y tile [m0:m0+128) x [n0:n0+256), 8 waves =================
    char* a_base = smem;            // [128][64] f16 swizzled (16 KiB)
    char* b_base = smem + 16384;    // [256][64] f16 swizzled (32 KiB)
    float* lds_ep = (float*)smem;   // epilogue reuse: [32][260] f32 (33 KiB)
    const int lane = tid & 63, wid = tid >> 6;
    const int wm = wid & 1, wn = wid >> 1;      // 2M x 4N waves: 64 rows x 64 cols each
    const int arow = tid >> 3, aseg = tid & 7;  // A: 64 rows/pass x 8 seg
    const int brow = tid >> 1, bseg = tid & 1;  // B: 256 rows x 2 seg (32 cols each)
    int fenced_t = -1;
    for (;;){
      if (tid == 0) sh_tile = atomicAdd(&ctl[2049], 1);
      __syncthreads();
      const int tile = sh_tile;
      if (tile >= NTILE) break;
      const int mg = tile / 125;
      const int ng = tile - mg*125;
      const int m0 = mg*128, n0 = ng*256;
      const int t_need = mg*4 + 3;
      if (tid == 0 && t_need > fenced_t){
        while (atomicAdd(&ctl[t_need*16], 0) < BB) __builtin_amdgcn_s_sleep(64);
        __threadfence();           // acquire before reading Hn16
        fenced_t = t_need;
      }
      __syncthreads();

      f32x4 acc[4][4];
      {
        f32x4 z = {0.f,0.f,0.f,0.f};
        #pragma unroll
        for (int i=0;i<4;i++)
          #pragma unroll
          for (int j=0;j<4;j++) acc[i][j] = z;
      }

      #pragma unroll 1
      for (int kt=0; kt<4; kt++){
        // stage A: 128x64 f16 (two passes of 64 rows)
        #pragma unroll
        for (int p=0;p<2;p++){
          int row = arow + p*64;
          uint4 av = *(const uint4*)(Hn16 + (size_t)(m0+row)*HH + kt*64 + aseg*8);
          *(uint4*)(a_base + ((row*128 + aseg*16) ^ ((row&7)<<4))) = av;
        }
        // stage B: 256x64 f16 from f32 (each thread 32 floats)
        {
          const float4* bs = (const float4*)(Wo + (size_t)(n0+brow)*HH + kt*64 + bseg*32);
          #pragma unroll
          for (int j=0;j<4;j++){
            float4 f0 = bs[2*j], f1 = bs[2*j+1];
            f16x8 hv;
            hv[0]=(f16)f0.x; hv[1]=(f16)f0.y; hv[2]=(f16)f0.z; hv[3]=(f16)f0.w;
            hv[4]=(f16)f1.x; hv[5]=(f16)f1.y; hv[6]=(f16)f1.z; hv[7]=(f16)f1.w;
            *(f16x8*)(b_base + ((brow*128 + bseg*64 + j*16) ^ ((brow&7)<<4))) = hv;
          }
        }
        __syncthreads();
        #pragma unroll
        for (int kk=0; kk<2; kk++){
          const int kbyte = kk*64 + (lane>>4)*16;
          f16x8 af[4], bf[4];
          #pragma unroll
          for (int mi=0;mi<4;mi++){
            int row = wm*64 + mi*16 + (lane&15);
            af[mi] = *(const f16x8*)(a_base + ((row*128 + kbyte) ^ ((row&7)<<4)));
          }
          #pragma unroll
          for (int nj=0;nj<4;nj++){
            int rb = wn*64 + nj*16 + (lane&15);
            bf[nj] = *(const f16x8*)(b_base + ((rb*128 + kbyte) ^ ((rb&7)<<4)));
          }
          #pragma unroll
          for (int mi=0;mi<4;mi++)
            #pragma unroll
            for (int nj=0;nj<4;nj++)
              acc[mi][nj] = __builtin_amdgcn_mfma_f32_16x16x32_f16(af[mi], bf[nj], acc[mi][nj], 0, 0, 0);
        }
        __syncthreads();
      }

      // ---- LDS-bounce epilogue: 4 chunks of 32 rows; 1KB contiguous stores per wave
      const float4 bo4 = *(const float4*)(bo + n0 + lane*4);
      #pragma unroll 1
      for (int c=0;c<4;c++){
        if (wm == (c>>1)){
          #pragma unroll
          for (int mi2=0;mi2<2;mi2++){
            int mi = (c&1)*2 + mi2;
            #pragma unroll
            for (int nj=0;nj<4;nj++){
              int col = wn*64 + nj*16 + (lane&15);
              #pragma unroll
              for (int r=0;r<4;r++){
                int lr = mi2*16 + (lane>>4)*4 + r;
                lds_ep[lr*260 + col] = acc[mi][nj][r];
              }
            }
          }
        }
        __syncthreads();
        #pragma unroll
        for (int i=0;i<4;i++){
          int lr = wid*4 + i;
          float4 v = *(const float4*)(lds_ep + lr*260 + lane*4);
          v.x += bo4.x; v.y += bo4.y; v.z += bo4.z; v.w += bo4.w;
          *(float4*)(Y + (size_t)(m0 + c*32 + lr)*VV + n0 + lane*4) = v;
        }
        __syncthreads();
      }
    }
  }
}

extern "C" void kernel_launch(void* const* d_in, const int* in_sizes, int n_in,
                              void* d_out, int out_size, void* d_ws, size_t ws_size,
                              hipStream_t stream){
  const int*   X  = (const int*)d_in[0];
  const float* H0 = (const float*)d_in[1];
  const float* Wz = (const float*)d_in[2];
  const float* bz = (const float*)d_in[3];
  const float* Wr = (const float*)d_in[4];
  const float* br = (const float*)d_in[5];
  const float* Wh = (const float*)d_in[6];
  const float* bh = (const float*)d_in[7];
  const float* Wo = (const float*)d_in[8];
  const float* bo = (const float*)d_in[9];
  float* out = (float*)d_out;

  char* ws = (char*)d_ws;
  float*    g_buf = (float*)ws;                               // 4096*768*4  = 12,582,912 B
  uint32_t* Wpack = (uint32_t*)(ws + 12582912);               // 512*192*4   =    393,216 B
  f16*      Hn16  = (f16*)(ws + 12582912 + 393216);           // 4096*256*2  =  2,097,152 B
  int*      ctl   = (int*)(ws + 12582912 + 393216 + 2097152); // 2050*4      ≈      8,200 B

  k_init<<<3, 1024, 0, stream>>>(ctl);
  k_gather<<<4096, 256, 0, stream>>>(X, Wz, bz, Wr, br, Wh, bh, g_buf);
  k_pack<<<384, 256, 0, stream>>>(Wz, Wr, Wh, Wpack);
  k_fused<<<256, 512, 0, stream>>>(H0, Wpack, g_buf, Wo, bo, Hn16, out, out + 131072000LL, ctl);
}

// Round 10
// 791.882 us; speedup vs baseline: 1.4543x; 1.4543x over previous
//
#include <hip/hip_runtime.h>
#include <hip/hip_fp16.h>
#include <stdint.h>

#define VV 32000
#define HH 256
#define BB 32
#define TT 128
#define VH 32256  // V + H

typedef _Float16 f16;
typedef _Float16 f16x2 __attribute__((ext_vector_type(2)));
typedef _Float16 f16x8 __attribute__((ext_vector_type(8)));
typedef float f32x4 __attribute__((ext_vector_type(4)));

static __device__ __forceinline__ float dot2f(uint32_t w, uint32_t h, float acc){
  f16x2 a = __builtin_bit_cast(f16x2, w);
  f16x2 b = __builtin_bit_cast(f16x2, h);
#if __has_builtin(__builtin_amdgcn_fdot2)
  return __builtin_amdgcn_fdot2(a, b, acc, false);
#else
  acc = fmaf((float)a[0], (float)b[0], acc);
  acc = fmaf((float)a[1], (float)b[1], acc);
  return acc;
#endif
}

// ---------------- gather: g[t*32+b][o] = W_gate[row][tok] + bias
__global__ void k_gather(const int* __restrict__ X,
                         const float* __restrict__ Wz, const float* __restrict__ bz,
                         const float* __restrict__ Wr, const float* __restrict__ br,
                         const float* __restrict__ Wh, const float* __restrict__ bh,
                         float* __restrict__ g_buf){
  int tb = blockIdx.x;              // t*32 + b
  int t = tb >> 5, b = tb & 31;
  int tok = X[b*TT + t];
  int o = threadIdx.x;              // 0..255
  g_buf[(size_t)tb*768 + o]       = Wz[(size_t)o*VH + tok] + bz[o];
  g_buf[(size_t)tb*768 + 256 + o] = Wr[(size_t)o*VH + tok] + br[o];
  g_buf[(size_t)tb*768 + 512 + o] = Wh[(size_t)o*VH + tok] + bh[o];
}

// ---------------- pack recurrent weights for 256-thread recurrence layout
// thread t: ko=t&7 (K-chunk [ko*32,ko*32+32)), no=t>>3 in [0,32)
// w1 (rem<256): ol=rem>>4 in [0,16): gate-row o=no*16+ol (o<256: Wz row o; else Wr row o-256)
// w2 (rem>=256): ol in [0,8): Wh row no*8+ol
// Wpack[t*384 + rem]: f16x2{ W[row][VV + ko*32 + 2p], W[row][VV + ko*32 + 2p + 1] }, p=rem&15
__global__ void k_pack(const float* __restrict__ Wz, const float* __restrict__ Wr,
                       const float* __restrict__ Wh, uint32_t* __restrict__ Wpack){
  int idx = blockIdx.x*256 + threadIdx.x;
  if (idx >= 256*384) return;
  int t = idx / 384, rem = idx - t*384;
  int ko = t & 7, no = t >> 3;
  const float* W; int row, p;
  if (rem < 256){
    int ol = rem >> 4; p = rem & 15;
    int o = no*16 + ol;
    if (o < 256){ W = Wz; row = o; } else { W = Wr; row = o - 256; }
  } else {
    int rem2 = rem - 256;
    int ol = rem2 >> 4; p = rem2 & 15;
    W = Wh; row = no*8 + ol;
  }
  int k = ko*32 + p*2;
  float a = W[(size_t)row*VH + VV + k];
  float c = W[(size_t)row*VH + VV + k + 1];
  f16x2 v; v[0] = (f16)a; v[1] = (f16)c;
  Wpack[idx] = __builtin_bit_cast(uint32_t, v);
}

// ---------------- recurrence: 32 blocks x 256 threads, waves_per_eu(1,1)
// 1 wave/SIMD -> 512-VGPR budget; 384-dword weight array + temps (~440) fits -> true residency
__global__ __launch_bounds__(256)
__attribute__((amdgpu_waves_per_eu(1, 1)))
void k_recur(const float* __restrict__ H0,
             const uint32_t* __restrict__ Wpack,
             const float* __restrict__ g_buf,
             f16* __restrict__ Hn16,
             float* __restrict__ hf_out){
  __shared__ __align__(16) uint32_t hs16[128];   // Hs as f16 pairs
  __shared__ __align__(16) f16 rHs16[256];       // r*Hs as f16
  __shared__ float hs32[256];                    // Hs f32 (state of record)
  __shared__ float z_s[256];

  const int b = blockIdx.x;
  const int tid = threadIdx.x;
  const int ko = tid & 7, no = tid >> 3;   // no in [0,32)

  // 384 packed weight dwords per thread (static indices)
  uint32_t w1[16][16];
  uint32_t w2[8][16];
  {
    const uint4* src = (const uint4*)(Wpack + (size_t)tid*384);
    #pragma unroll
    for (int j=0;j<64;j++){
      uint4 v = src[j];
      int f = j*4;
      w1[(f+0)>>4][(f+0)&15] = v.x;
      w1[(f+1)>>4][(f+1)&15] = v.y;
      w1[(f+2)>>4][(f+2)&15] = v.z;
      w1[(f+3)>>4][(f+3)&15] = v.w;
    }
    #pragma unroll
    for (int j=0;j<32;j++){
      uint4 v = src[64 + j];
      int f = j*4;
      w2[(f+0)>>4][(f+0)&15] = v.x;
      w2[(f+1)>>4][(f+1)&15] = v.y;
      w2[(f+2)>>4][(f+2)&15] = v.z;
      w2[(f+3)>>4][(f+3)&15] = v.w;
    }
  }

  hs32[tid] = H0[b*HH + tid];
  __syncthreads();
  if (tid < 128){
    f16x2 v; v[0] = (f16)hs32[2*tid]; v[1] = (f16)hs32[2*tid+1];
    hs16[tid] = __builtin_bit_cast(uint32_t, v);
  }
  __syncthreads();

  // per-lane gate-input prefetch: this thread's own outputs
  const int gi1a = no*16 + ko;           // phase-1 output A (z or r row)
  const int gi1b = no*16 + 8 + ko;       // phase-1 output B
  const int gi2  = 512 + no*8 + ko;      // phase-2 output
  float g1a = g_buf[(size_t)b*768 + gi1a];
  float g1b = g_buf[(size_t)b*768 + gi1b];
  float g2  = g_buf[(size_t)b*768 + gi2];
  float g1an = 0.f, g1bn = 0.f, g2n = 0.f;

  for (int t = 0; t < TT; t++){
    if (t < TT-1){
      const float* gn = g_buf + (size_t)((t+1)*BB + b)*768;
      g1an = gn[gi1a];
      g1bn = gn[gi1b];
      g2n  = gn[gi2];
    }

    // ---- phase 1: z (no<16) and r (no>=16) pre-activations, 16 outputs per group
    uint32_t hp[16];
    {
      const uint4* hsp = (const uint4*)hs16;
      #pragma unroll
      for (int j=0;j<4;j++){
        uint4 v = hsp[ko*4 + j];
        hp[4*j] = v.x; hp[4*j+1] = v.y; hp[4*j+2] = v.z; hp[4*j+3] = v.w;
      }
    }
    float acc[16];
    #pragma unroll
    for (int ol=0;ol<16;ol++) acc[ol] = 0.f;
    #pragma unroll
    for (int p=0;p<16;p++)
      #pragma unroll
      for (int ol=0;ol<16;ol++)
        acc[ol] = dot2f(w1[ol][p], hp[p], acc[ol]);
    #pragma unroll
    for (int ol=0;ol<16;ol++){
      float v2 = acc[ol];
      v2 += __shfl_xor(v2, 1);
      v2 += __shfl_xor(v2, 2);
      v2 += __shfl_xor(v2, 4);
      acc[ol] = v2;
    }
    // lane ko takes outputs ol=ko and ol=ko+8 (select chains, no dynamic indexing)
    {
      float sa = acc[0], sb = acc[8];
      #pragma unroll
      for (int ol=1;ol<8;ol++){
        sa = (ko == ol) ? acc[ol]   : sa;
        sb = (ko == ol) ? acc[ol+8] : sb;
      }
      float prea = sa + g1a;
      float preb = sb + g1b;
      float va = 1.f / (1.f + __expf(-prea));
      float vb = 1.f / (1.f + __expf(-preb));
      int oa = no*16 + ko;
      int ob = no*16 + 8 + ko;
      if (no < 16){
        z_s[oa] = va;
        z_s[ob] = vb;
      } else {
        int opa = oa - 256, opb = ob - 256;
        rHs16[opa] = (f16)(va * hs32[opa]);
        rHs16[opb] = (f16)(vb * hs32[opb]);
      }
    }
    __syncthreads();

    // ---- phase 2: h~ = tanh(gh + (r*Hs)@Wh^T), Hn = z*h~ + (1-z)*Hs; 8 outputs/group
    uint32_t rp[16];
    {
      const uint4* rpp = (const uint4*)rHs16;
      #pragma unroll
      for (int j=0;j<4;j++){
        uint4 v = rpp[ko*4 + j];
        rp[4*j] = v.x; rp[4*j+1] = v.y; rp[4*j+2] = v.z; rp[4*j+3] = v.w;
      }
    }
    float a2[8];
    #pragma unroll
    for (int oi=0;oi<8;oi++) a2[oi] = 0.f;
    #pragma unroll
    for (int p=0;p<16;p++)
      #pragma unroll
      for (int oi=0;oi<8;oi++)
        a2[oi] = dot2f(w2[oi][p], rp[p], a2[oi]);
    #pragma unroll
    for (int oi=0;oi<8;oi++){
      float v2 = a2[oi];
      v2 += __shfl_xor(v2, 1);
      v2 += __shfl_xor(v2, 2);
      v2 += __shfl_xor(v2, 4);
      a2[oi] = v2;
    }
    {
      float sel = a2[0];
      #pragma unroll
      for (int oi=1;oi<8;oi++) sel = (ko == oi) ? a2[oi] : sel;
      int o = no*8 + ko;                  // all 256 threads: one output each
      float pre = sel + g2;
      float ax = fabsf(pre);
      float e = __expf(2.f*ax);
      float th = 1.f - 2.f/(e + 1.f);     // tanh(|x|), safe at inf
      th = copysignf(th, pre);
      float z = z_s[o];
      float hn = z*th + (1.f - z)*hs32[o];
      hs32[o] = hn;
      ((f16*)hs16)[o] = (f16)hn;
      Hn16[(size_t)(t*BB + b)*HH + o] = (f16)hn;
      if (t == TT-1) hf_out[b*HH + o] = hn;
    }
    g1a = g1an; g1b = g1bn; g2 = g2n;
    __syncthreads();
  }
}

// ---------------- output GEMM: Y[4096][32000] = Hn16[4096][256] @ Wo^T (f16 MFMA) + bo
__global__ __launch_bounds__(256) void k_gemm(const f16* __restrict__ A, const float* __restrict__ Wo,
                                              const float* __restrict__ bo, float* __restrict__ Y){
  __shared__ __align__(16) f16 a_lds[128*128];
  __shared__ __align__(16) f16 b_lds[128*128];
  const int m0 = blockIdx.x * 128;   // m fastest -> consecutive blocks share Wo n-panel in L2
  const int n0 = blockIdx.y * 128;
  const int tid = threadIdx.x;
  const int lane = tid & 63, wave = tid >> 6;
  const int wm = wave >> 1, wn = wave & 1;

  f32x4 acc[4][4];
  {
    f32x4 z = {0.f, 0.f, 0.f, 0.f};
    #pragma unroll
    for (int i=0;i<4;i++)
      #pragma unroll
      for (int j=0;j<4;j++) acc[i][j] = z;
  }

  const int srow = tid >> 1, seg = tid & 1;
  #pragma unroll 1
  for (int kt=0; kt<2; kt++){
    const int k0 = kt*128;
    {
      const uint4* asrc = (const uint4*)(A + (size_t)(m0+srow)*256 + k0 + seg*64);
      #pragma unroll
      for (int j=0;j<8;j++){
        uint4 v = asrc[j];
        int byte = (srow*256 + seg*128 + j*16) ^ ((srow&7)<<4);
        *(uint4*)((char*)a_lds + byte) = v;
      }
      const float4* bsrc = (const float4*)(Wo + (size_t)(n0+srow)*256 + k0 + seg*64);
      #pragma unroll
      for (int j=0;j<8;j++){
        float4 f0 = bsrc[2*j], f1 = bsrc[2*j+1];
        f16x8 hv;
        hv[0]=(f16)f0.x; hv[1]=(f16)f0.y; hv[2]=(f16)f0.z; hv[3]=(f16)f0.w;
        hv[4]=(f16)f1.x; hv[5]=(f16)f1.y; hv[6]=(f16)f1.z; hv[7]=(f16)f1.w;
        int byte = (srow*256 + seg*128 + j*16) ^ ((srow&7)<<4);
        *(f16x8*)((char*)b_lds + byte) = hv;
      }
    }
    __syncthreads();
    #pragma unroll
    for (int kk=0; kk<4; kk++){
      const int kbyte = kk*64 + (lane>>4)*16;
      f16x8 af[4], bf[4];
      #pragma unroll
      for (int mi=0;mi<4;mi++){
        int row = wm*64 + mi*16 + (lane&15);
        int byte = (row*256 + kbyte) ^ ((row&7)<<4);
        af[mi] = *(const f16x8*)((const char*)a_lds + byte);
      }
      #pragma unroll
      for (int nj=0;nj<4;nj++){
        int nl = wn*64 + nj*16 + (lane&15);
        int byte = (nl*256 + kbyte) ^ ((nl&7)<<4);
        bf[nj] = *(const f16x8*)((const char*)b_lds + byte);
      }
      #pragma unroll
      for (int mi=0;mi<4;mi++)
        #pragma unroll
        for (int nj=0;nj<4;nj++)
          acc[mi][nj] = __builtin_amdgcn_mfma_f32_16x16x32_f16(af[mi], bf[nj], acc[mi][nj], 0, 0, 0);
    }
    __syncthreads();
  }
  // epilogue: C/D map: col = lane&15, row = (lane>>4)*4 + reg
  #pragma unroll
  for (int nj=0;nj<4;nj++){
    const int col = n0 + wn*64 + nj*16 + (lane & 15);
    const float bov = bo[col];
    #pragma unroll
    for (int mi=0;mi<4;mi++){
      const int rbase = m0 + wm*64 + mi*16 + (lane>>4)*4;
      #pragma unroll
      for (int r=0;r<4;r++){
        Y[(size_t)(rbase + r)*VV + col] = acc[mi][nj][r] + bov;
      }
    }
  }
}

extern "C" void kernel_launch(void* const* d_in, const int* in_sizes, int n_in,
                              void* d_out, int out_size, void* d_ws, size_t ws_size,
                              hipStream_t stream){
  const int*   X  = (const int*)d_in[0];
  const float* H0 = (const float*)d_in[1];
  const float* Wz = (const float*)d_in[2];
  const float* bz = (const float*)d_in[3];
  const float* Wr = (const float*)d_in[4];
  const float* br = (const float*)d_in[5];
  const float* Wh = (const float*)d_in[6];
  const float* bh = (const float*)d_in[7];
  const float* Wo = (const float*)d_in[8];
  const float* bo = (const float*)d_in[9];
  float* out = (float*)d_out;

  char* ws = (char*)d_ws;
  float*    g_buf = (float*)ws;                               // 4096*768*4  = 12,582,912 B
  uint32_t* Wpack = (uint32_t*)(ws + 12582912);               // 256*384*4   =    393,216 B
  f16*      Hn16  = (f16*)(ws + 12582912 + 393216);           // 4096*256*2  =  2,097,152 B

  k_gather<<<4096, 256, 0, stream>>>(X, Wz, bz, Wr, br, Wh, bh, g_buf);
  k_pack<<<384, 256, 0, stream>>>(Wz, Wr, Wh, Wpack);
  k_recur<<<32, 256, 0, stream>>>(H0, Wpack, g_buf, Hn16, out + 131072000LL);
  k_gemm<<<dim3(32, 250), 256, 0, stream>>>(Hn16, Wo, bo, out);
}

// Round 11
// 612.014 us; speedup vs baseline: 1.8818x; 1.2939x over previous
//
#include <hip/hip_runtime.h>
#include <hip/hip_fp16.h>
#include <stdint.h>

#define VV 32000
#define HH 256
#define BB 32
#define TT 128
#define VH 32256  // V + H

typedef _Float16 f16;
typedef _Float16 f16x2 __attribute__((ext_vector_type(2)));
typedef _Float16 f16x8 __attribute__((ext_vector_type(8)));
typedef float f32x4 __attribute__((ext_vector_type(4)));

static __device__ __forceinline__ float dot2f(uint32_t w, uint32_t h, float acc){
  f16x2 a = __builtin_bit_cast(f16x2, w);
  f16x2 b = __builtin_bit_cast(f16x2, h);
#if __has_builtin(__builtin_amdgcn_fdot2)
  return __builtin_amdgcn_fdot2(a, b, acc, false);
#else
  acc = fmaf((float)a[0], (float)b[0], acc);
  acc = fmaf((float)a[1], (float)b[1], acc);
  return acc;
#endif
}

// ---------------- gather: g[t*32+b][o] = W_gate[row][tok] + bias
__global__ void k_gather(const int* __restrict__ X,
                         const float* __restrict__ Wz, const float* __restrict__ bz,
                         const float* __restrict__ Wr, const float* __restrict__ br,
                         const float* __restrict__ Wh, const float* __restrict__ bh,
                         float* __restrict__ g_buf){
  int tb = blockIdx.x;              // t*32 + b
  int t = tb >> 5, b = tb & 31;
  int tok = X[b*TT + t];
  int o = threadIdx.x;              // 0..255
  g_buf[(size_t)tb*768 + o]       = Wz[(size_t)o*VH + tok] + bz[o];
  g_buf[(size_t)tb*768 + 256 + o] = Wr[(size_t)o*VH + tok] + br[o];
  g_buf[(size_t)tb*768 + 512 + o] = Wh[(size_t)o*VH + tok] + bh[o];
}

// ---------------- pack Wz/Wr for register residency (512-thread layout)
// thread t: ko=t&7, no=t>>3 in [0,64); ol in [0,8): row o=no*8+ol (o<256: Wz o; else Wr o-256)
// Wpack1[t*128 + ol*16 + p] = f16x2{ W[row][VV + ko*32 + 2p], W[row][VV + ko*32 + 2p+1] }
__global__ void k_pack1(const float* __restrict__ Wz, const float* __restrict__ Wr,
                        uint32_t* __restrict__ Wpack1){
  int idx = blockIdx.x*256 + threadIdx.x;
  if (idx >= 512*128) return;
  int t = idx >> 7, rem = idx & 127;
  int ol = rem >> 4, p = rem & 15;
  int ko = t & 7, no = t >> 3;
  int k = ko*32 + p*2;
  int o = no*8 + ol;
  const float* W; int row;
  if (o < 256){ W = Wz; row = o; } else { W = Wr; row = o - 256; }
  float a = W[(size_t)row*VH + VV + k];
  float c = W[(size_t)row*VH + VV + k + 1];
  f16x2 v; v[0] = (f16)a; v[1] = (f16)c;
  Wpack1[idx] = __builtin_bit_cast(uint32_t, v);
}

// ---------------- pack Wh in dword-plane layout for LDS residency
// Wpack2[j*512 + t]: j=oi*16+p -> row=(t>>3)*4+oi, k=(t&7)*32+2p
__global__ void k_pack2(const float* __restrict__ Wh, uint32_t* __restrict__ Wpack2){
  int idx = blockIdx.x*256 + threadIdx.x;
  if (idx >= 64*512) return;
  int j = idx >> 9, t = idx & 511;
  int oi = j >> 4, p = j & 15;
  int row = (t >> 3)*4 + oi;
  int k = (t & 7)*32 + p*2;
  float a = Wh[(size_t)row*VH + VV + k];
  float c = Wh[(size_t)row*VH + VV + k + 1];
  f16x2 v; v[0] = (f16)a; v[1] = (f16)c;
  Wpack2[idx] = __builtin_bit_cast(uint32_t, v);
}

// ---------------- recurrence: 32 blocks x 512 threads, waves_per_eu(2,2)
// Wz/Wr in registers (128 dwords/thread, ~185 total demand < 248 proven cap);
// Wh in LDS (136 KB total), conflict-free dword-plane reads.
__global__ __launch_bounds__(512)
__attribute__((amdgpu_waves_per_eu(2, 2)))
void k_recur(const float* __restrict__ H0,
             const uint32_t* __restrict__ Wpack1,
             const uint32_t* __restrict__ Wpack2,
             const float* __restrict__ g_buf,
             f16* __restrict__ Hn16,
             float* __restrict__ hf_out){
  __shared__ uint32_t whlds[64*520];             // 133,120 B: Wh planes, pad 8 -> conflict-free
  __shared__ __align__(16) uint32_t hs16[128];   // Hs as f16 pairs
  __shared__ __align__(16) f16 rHs16[256];       // r*Hs as f16
  __shared__ float hs32[256];                    // Hs f32 (state of record)
  __shared__ float z_s[256];

  const int b = blockIdx.x;
  const int tid = threadIdx.x;
  const int ko = tid & 7, no = tid >> 3;   // no in [0,64)

  // stage Wh into LDS (one-time, coalesced, conflict-free writes)
  #pragma unroll
  for (int j=0;j<64;j++) whlds[j*520 + tid] = Wpack2[j*512 + tid];

  // 128 packed Wz/Wr dwords per thread (static indices -> registers)
  uint32_t w1[8][16];
  {
    const uint4* src = (const uint4*)(Wpack1 + (size_t)tid*128);
    #pragma unroll
    for (int j=0;j<32;j++){
      uint4 v = src[j];
      int f = j*4;
      w1[(f+0)>>4][(f+0)&15] = v.x;
      w1[(f+1)>>4][(f+1)&15] = v.y;
      w1[(f+2)>>4][(f+2)&15] = v.z;
      w1[(f+3)>>4][(f+3)&15] = v.w;
    }
  }

  if (tid < 256) hs32[tid] = H0[b*HH + tid];
  __syncthreads();
  if (tid < 128){
    f16x2 v; v[0] = (f16)hs32[2*tid]; v[1] = (f16)hs32[2*tid+1];
    hs16[tid] = __builtin_bit_cast(uint32_t, v);
  }
  __syncthreads();

  // per-lane gate-input prefetch
  const int gi1 = no*8 + ko;                 // phase-1 output of this lane
  const int gi2 = 512 + no*4 + (ko & 3);     // phase-2 output (lanes ko<4)
  float g1 = g_buf[(size_t)b*768 + gi1];
  float g2 = g_buf[(size_t)b*768 + gi2];
  float g1n = 0.f, g2n = 0.f;

  const uint32_t* wh = whlds + tid;

  for (int t = 0; t < TT; t++){
    if (t < TT-1){
      const float* gn = g_buf + (size_t)((t+1)*BB + b)*768;
      g1n = gn[gi1];
      g2n = gn[gi2];
    }

    // ---- phase 1: z (no<32) and r (no>=32) pre-activations, 8 outputs per group
    uint32_t hp[16];
    {
      const uint2* hsp = (const uint2*)hs16;
      #pragma unroll
      for (int j=0;j<8;j++){ uint2 v = hsp[ko*8 + j]; hp[2*j] = v.x; hp[2*j+1] = v.y; }
    }
    float acc[8];
    #pragma unroll
    for (int ol=0;ol<8;ol++) acc[ol] = 0.f;
    #pragma unroll
    for (int p=0;p<16;p++)
      #pragma unroll
      for (int ol=0;ol<8;ol++)
        acc[ol] = dot2f(w1[ol][p], hp[p], acc[ol]);
    #pragma unroll
    for (int ol=0;ol<8;ol++){
      float v2 = acc[ol];
      v2 += __shfl_xor(v2, 1);
      v2 += __shfl_xor(v2, 2);
      v2 += __shfl_xor(v2, 4);
      acc[ol] = v2;
    }
    {
      float sel = acc[0];
      #pragma unroll
      for (int ol=1;ol<8;ol++) sel = (ko == ol) ? acc[ol] : sel;
      float pre = sel + g1;
      float s = 1.f / (1.f + __expf(-pre));
      int o = no*8 + ko;
      if (no < 32){
        z_s[o] = s;
      } else {
        int op = o - 256;
        rHs16[op] = (f16)(s * hs32[op]);
      }
    }
    __syncthreads();

    // ---- phase 2: h~ = tanh(gh + (r*Hs)@Wh^T); Wh from LDS planes
    uint32_t rp[16];
    {
      const uint2* rpp = (const uint2*)rHs16;
      #pragma unroll
      for (int j=0;j<8;j++){ uint2 v = rpp[ko*8 + j]; rp[2*j] = v.x; rp[2*j+1] = v.y; }
    }
    float a2[4];
    #pragma unroll
    for (int oi=0;oi<4;oi++) a2[oi] = 0.f;
    #pragma unroll
    for (int p=0;p<16;p++)
      #pragma unroll
      for (int oi=0;oi<4;oi++)
        a2[oi] = dot2f(wh[(oi*16 + p)*520], rp[p], a2[oi]);
    #pragma unroll
    for (int oi=0;oi<4;oi++){
      float v2 = a2[oi];
      v2 += __shfl_xor(v2, 1);
      v2 += __shfl_xor(v2, 2);
      v2 += __shfl_xor(v2, 4);
      a2[oi] = v2;
    }
    if (ko < 4){
      float sel = a2[0];
      #pragma unroll
      for (int oi=1;oi<4;oi++) sel = (ko == oi) ? a2[oi] : sel;
      int o = no*4 + ko;
      float pre = sel + g2;
      float ax = fabsf(pre);
      float e = __expf(2.f*ax);
      float th = 1.f - 2.f/(e + 1.f);      // tanh(|x|), safe at inf
      th = copysignf(th, pre);
      float z = z_s[o];
      float hn = z*th + (1.f - z)*hs32[o];
      hs32[o] = hn;
      ((f16*)hs16)[o] = (f16)hn;
      Hn16[(size_t)(t*BB + b)*HH + o] = (f16)hn;
      if (t == TT-1) hf_out[b*HH + o] = hn;
    }
    g1 = g1n; g2 = g2n;
    __syncthreads();
  }
}

// ---------------- output GEMM: Y[4096][32000] = Hn16[4096][256] @ Wo^T (f16 MFMA) + bo
__global__ __launch_bounds__(256) void k_gemm(const f16* __restrict__ A, const float* __restrict__ Wo,
                                              const float* __restrict__ bo, float* __restrict__ Y){
  __shared__ __align__(16) f16 a_lds[128*128];
  __shared__ __align__(16) f16 b_lds[128*128];
  const int m0 = blockIdx.x * 128;   // m fastest -> consecutive blocks share Wo n-panel in L2
  const int n0 = blockIdx.y * 128;
  const int tid = threadIdx.x;
  const int lane = tid & 63, wave = tid >> 6;
  const int wm = wave >> 1, wn = wave & 1;

  f32x4 acc[4][4];
  {
    f32x4 z = {0.f, 0.f, 0.f, 0.f};
    #pragma unroll
    for (int i=0;i<4;i++)
      #pragma unroll
      for (int j=0;j<4;j++) acc[i][j] = z;
  }

  const int srow = tid >> 1, seg = tid & 1;
  #pragma unroll 1
  for (int kt=0; kt<2; kt++){
    const int k0 = kt*128;
    {
      const uint4* asrc = (const uint4*)(A + (size_t)(m0+srow)*256 + k0 + seg*64);
      #pragma unroll
      for (int j=0;j<8;j++){
        uint4 v = asrc[j];
        int byte = (srow*256 + seg*128 + j*16) ^ ((srow&7)<<4);
        *(uint4*)((char*)a_lds + byte) = v;
      }
      const float4* bsrc = (const float4*)(Wo + (size_t)(n0+srow)*256 + k0 + seg*64);
      #pragma unroll
      for (int j=0;j<8;j++){
        float4 f0 = bsrc[2*j], f1 = bsrc[2*j+1];
        f16x8 hv;
        hv[0]=(f16)f0.x; hv[1]=(f16)f0.y; hv[2]=(f16)f0.z; hv[3]=(f16)f0.w;
        hv[4]=(f16)f1.x; hv[5]=(f16)f1.y; hv[6]=(f16)f1.z; hv[7]=(f16)f1.w;
        int byte = (srow*256 + seg*128 + j*16) ^ ((srow&7)<<4);
        *(f16x8*)((char*)b_lds + byte) = hv;
      }
    }
    __syncthreads();
    #pragma unroll
    for (int kk=0; kk<4; kk++){
      const int kbyte = kk*64 + (lane>>4)*16;
      f16x8 af[4], bf[4];
      #pragma unroll
      for (int mi=0;mi<4;mi++){
        int row = wm*64 + mi*16 + (lane&15);
        int byte = (row*256 + kbyte) ^ ((row&7)<<4);
        af[mi] = *(const f16x8*)((const char*)a_lds + byte);
      }
      #pragma unroll
      for (int nj=0;nj<4;nj++){
        int nl = wn*64 + nj*16 + (lane&15);
        int byte = (nl*256 + kbyte) ^ ((nl&7)<<4);
        bf[nj] = *(const f16x8*)((const char*)b_lds + byte);
      }
      #pragma unroll
      for (int mi=0;mi<4;mi++)
        #pragma unroll
        for (int nj=0;nj<4;nj++)
          acc[mi][nj] = __builtin_amdgcn_mfma_f32_16x16x32_f16(af[mi], bf[nj], acc[mi][nj], 0, 0, 0);
    }
    __syncthreads();
  }
  // epilogue: C/D map: col = lane&15, row = (lane>>4)*4 + reg
  #pragma unroll
  for (int nj=0;nj<4;nj++){
    const int col = n0 + wn*64 + nj*16 + (lane & 15);
    const float bov = bo[col];
    #pragma unroll
    for (int mi=0;mi<4;mi++){
      const int rbase = m0 + wm*64 + mi*16 + (lane>>4)*4;
      #pragma unroll
      for (int r=0;r<4;r++){
        Y[(size_t)(rbase + r)*VV + col] = acc[mi][nj][r] + bov;
      }
    }
  }
}

extern "C" void kernel_launch(void* const* d_in, const int* in_sizes, int n_in,
                              void* d_out, int out_size, void* d_ws, size_t ws_size,
                              hipStream_t stream){
  const int*   X  = (const int*)d_in[0];
  const float* H0 = (const float*)d_in[1];
  const float* Wz = (const float*)d_in[2];
  const float* bz = (const float*)d_in[3];
  const float* Wr = (const float*)d_in[4];
  const float* br = (const float*)d_in[5];
  const float* Wh = (const float*)d_in[6];
  const float* bh = (const float*)d_in[7];
  const float* Wo = (const float*)d_in[8];
  const float* bo = (const float*)d_in[9];
  float* out = (float*)d_out;

  char* ws = (char*)d_ws;
  float*    g_buf  = (float*)ws;                        // 4096*768*4 = 12,582,912 B
  uint32_t* Wpack1 = (uint32_t*)(ws + 12582912);        // 512*128*4  =    262,144 B
  uint32_t* Wpack2 = (uint32_t*)(ws + 12845056);        // 64*512*4   =    131,072 B
  f16*      Hn16   = (f16*)(ws + 12976128);             // 4096*256*2 =  2,097,152 B

  k_gather<<<4096, 256, 0, stream>>>(X, Wz, bz, Wr, br, Wh, bh, g_buf);
  k_pack1<<<256, 256, 0, stream>>>(Wz, Wr, Wpack1);
  k_pack2<<<128, 256, 0, stream>>>(Wh, Wpack2);
  k_recur<<<32, 512, 0, stream>>>(H0, Wpack1, Wpack2, g_buf, Hn16, out + 131072000LL);
  k_gemm<<<dim3(32, 250), 256, 0, stream>>>(Hn16, Wo, bo, out);
}